// Round 6
// baseline (438.951 us; speedup 1.0000x reference)
//
#include <hip/hip_runtime.h>

#define N_NODES 50000
#define MP      50048        // N_NODES padded to multiple of 128
#define N_EDGES 800000
#define NFEAT   512
#define NHID    256
#define NOUT    64

typedef __bf16 bf16x8 __attribute__((ext_vector_type(8)));
typedef float  f32x4  __attribute__((ext_vector_type(4)));

__device__ __forceinline__ unsigned short f2bf(float f) {
    __bf16 b = (__bf16)f;                       // RNE
    return __builtin_bit_cast(unsigned short, b);
}

__device__ __forceinline__ bf16x8 pack8(float4 a, float4 b) {
    uint4 o;
    o.x = (unsigned)f2bf(a.x) | ((unsigned)f2bf(a.y) << 16);
    o.y = (unsigned)f2bf(a.z) | ((unsigned)f2bf(a.w) << 16);
    o.z = (unsigned)f2bf(b.x) | ((unsigned)f2bf(b.y) << 16);
    o.w = (unsigned)f2bf(b.z) | ((unsigned)f2bf(b.w) << 16);
    return __builtin_bit_cast(bf16x8, o);
}

// ---------------------------------------------------------------------------
// prep: fused rowptr + w1 transpose + w2 transpose + h1 pad zero. 820 blocks.
// ---------------------------------------------------------------------------
__global__ __launch_bounds__(256) void prep(const int* __restrict__ row,
                                            int* __restrict__ rp,
                                            const float* __restrict__ w1,
                                            __bf16* __restrict__ w1t,
                                            const float* __restrict__ w2,
                                            __bf16* __restrict__ w2t,
                                            __bf16* __restrict__ h1) {
    const int b = blockIdx.x, t = threadIdx.x;
    if (b < 196) {
        int r = b * 256 + t;
        if (r <= N_NODES) {
            int lo = 0, hi = N_EDGES;
            while (lo < hi) {
                int mid = (lo + hi) >> 1;
                if (row[mid] < r) lo = mid + 1; else hi = mid;
            }
            rp[r] = lo;
        }
    } else if (b < 708) {
        int o = (b - 196) * 256 + t;          // n = o>>9, k = o&511
        w1t[o] = (__bf16)w1[(size_t)(o & 511) * NHID + (o >> 9)];
    } else if (b < 772) {
        int o = (b - 708) * 256 + t;          // n = o>>8, k = o&255
        w2t[o] = (__bf16)w2[(size_t)(o & 255) * NOUT + (o >> 8)];
    } else {
        int o = (b - 772) * 256 + t;
        h1[(size_t)N_NODES * NHID + o] = (__bf16)0.f;
    }
}

// ---------------------------------------------------------------------------
// GEMM1, barrier-free: C[MP][256] bf16 = bf16(X[·][512] fp32) @ w1t[256][512]^T
// No LDS. Each wave loads MFMA fragments directly from global:
//   A: 32 B fp32 per lane per m-tile (16 rows x 128 B contiguous per wave),
//      converted to bf16 in regs. B: 16 B per lane, w1t is L2-resident.
// Block = 4 waves in 2x2 -> 64 rows x 256 cols. Grid 782.
// ---------------------------------------------------------------------------
__global__ __launch_bounds__(256) void gemm1_direct(const float* __restrict__ X,
                                                    const __bf16* __restrict__ Bt,
                                                    __bf16* __restrict__ C) {
    const int t = threadIdx.x;
    const int w = t >> 6, l = t & 63;
    const int wm = w >> 1, wn = w & 1;
    const int ml = l & 15, quad = l >> 4;
    const int row0 = blockIdx.x * 64;

    const int m0 = row0 + wm * 32 + ml;       // A row, mi=0 tile
    const bool v0 = (m0 < N_NODES);
    const bool v1 = (m0 + 16 < N_NODES);
    const float*  a0p = X  + (size_t)m0 * NFEAT + quad * 8;
    const float*  a1p = a0p + (size_t)16 * NFEAT;
    const __bf16* bp  = Bt + (size_t)(wn * 128 + ml) * NFEAT + quad * 8;

    f32x4 acc[2][8] = {};
    const float4 z4 = make_float4(0.f, 0.f, 0.f, 0.f);

    #pragma unroll 2
    for (int k0 = 0; k0 < NFEAT; k0 += 32) {
        float4 xa0 = v0 ? *(const float4*)(a0p + k0)     : z4;
        float4 xb0 = v0 ? *(const float4*)(a0p + k0 + 4) : z4;
        float4 xa1 = v1 ? *(const float4*)(a1p + k0)     : z4;
        float4 xb1 = v1 ? *(const float4*)(a1p + k0 + 4) : z4;
        bf16x8 bfr[8];
        #pragma unroll
        for (int ni = 0; ni < 8; ni++)
            bfr[ni] = *(const bf16x8*)(bp + (size_t)ni * 16 * NFEAT + k0);
        bf16x8 af[2];
        af[0] = pack8(xa0, xb0);
        af[1] = pack8(xa1, xb1);
        #pragma unroll
        for (int mi = 0; mi < 2; mi++)
            #pragma unroll
            for (int ni = 0; ni < 8; ni++)
                acc[mi][ni] = __builtin_amdgcn_mfma_f32_16x16x32_bf16(
                    af[mi], bfr[ni], acc[mi][ni], 0, 0, 0);
    }

    // C/D layout: col = lane&15, row = quad*4 + reg
    #pragma unroll
    for (int mi = 0; mi < 2; mi++) {
        int gr = row0 + wm * 32 + mi * 16 + quad * 4;
        #pragma unroll
        for (int ni = 0; ni < 8; ni++) {
            int gc = wn * 128 + ni * 16 + ml;
            #pragma unroll
            for (int r2 = 0; r2 < 4; r2++)
                C[(size_t)(gr + r2) * NHID + gc] = (__bf16)acc[mi][ni][r2];
        }
    }
}

// ---------------------------------------------------------------------------
// GEMM2, barrier-free: C[MP][64] bf16 = h1[MP][256] @ w2t[64][256]^T.
// Wave = 16 rows x 64 cols (1x4 MFMA tiles). Block 4 waves stacked in M.
// Grid 782. h1 pad rows are zeroed so no row guard needed.
// ---------------------------------------------------------------------------
__global__ __launch_bounds__(256) void gemm2_direct(const __bf16* __restrict__ A,
                                                    const __bf16* __restrict__ Bt,
                                                    __bf16* __restrict__ C) {
    const int t = threadIdx.x;
    const int w = t >> 6, l = t & 63;
    const int ml = l & 15, quad = l >> 4;
    const int row0 = blockIdx.x * 64;

    const __bf16* ap = A  + (size_t)(row0 + w * 16 + ml) * NHID + quad * 8;
    const __bf16* bp = Bt + (size_t)ml * NHID + quad * 8;

    f32x4 acc[4] = {};

    #pragma unroll
    for (int k0 = 0; k0 < NHID; k0 += 32) {
        bf16x8 af = *(const bf16x8*)(ap + k0);
        bf16x8 bfr[4];
        #pragma unroll
        for (int ni = 0; ni < 4; ni++)
            bfr[ni] = *(const bf16x8*)(bp + (size_t)ni * 16 * NHID + k0);
        #pragma unroll
        for (int ni = 0; ni < 4; ni++)
            acc[ni] = __builtin_amdgcn_mfma_f32_16x16x32_bf16(
                af, bfr[ni], acc[ni], 0, 0, 0);
    }

    #pragma unroll
    for (int ni = 0; ni < 4; ni++) {
        int gc = ni * 16 + ml;
        #pragma unroll
        for (int r2 = 0; r2 < 4; r2++) {
            int gr = row0 + w * 16 + quad * 4 + r2;
            C[(size_t)gr * NOUT + gc] = (__bf16)acc[ni][r2];
        }
    }
}

// ---------------------------------------------------------------------------
// SpMM1 + bias + ReLU: one wave per node. Half-wave (32 lanes) per edge,
// 16 B/lane (8 bf16 feats). Unrolled x4 -> 8 edges in flight per wave.
// ---------------------------------------------------------------------------
__global__ __launch_bounds__(256) void spmm1_wave(const __bf16* __restrict__ h0,
                                                  const float* __restrict__ ew,
                                                  const int* __restrict__ col,
                                                  const int* __restrict__ rp,
                                                  const float* __restrict__ b1,
                                                  __bf16* __restrict__ h1) {
    const int n    = blockIdx.x * 4 + (threadIdx.x >> 6);
    const int lane = threadIdx.x & 63;
    const int half = lane >> 5;
    const int fl   = lane & 31;       // 8 bf16 feats per lane
    const int s = rp[n], e = rp[n + 1];

    float acc[8] = {};
    int i = s + half;
    for (; i + 6 < e; i += 8) {
        int   c0 = col[i],     c1 = col[i + 2], c2 = col[i + 4], c3 = col[i + 6];
        float w0 = ew[i],      w1 = ew[i + 2],  w2 = ew[i + 4],  w3 = ew[i + 6];
        uint4 v0 = *(const uint4*)(h0 + (size_t)c0 * NHID + fl * 8);
        uint4 v1 = *(const uint4*)(h0 + (size_t)c1 * NHID + fl * 8);
        uint4 v2 = *(const uint4*)(h0 + (size_t)c2 * NHID + fl * 8);
        uint4 v3 = *(const uint4*)(h0 + (size_t)c3 * NHID + fl * 8);
        const unsigned* p0 = &v0.x; const unsigned* p1 = &v1.x;
        const unsigned* p2 = &v2.x; const unsigned* p3 = &v3.x;
        #pragma unroll
        for (int j = 0; j < 4; j++) {
            acc[2*j+0] += w0 * __builtin_bit_cast(float, p0[j] << 16)
                        + w1 * __builtin_bit_cast(float, p1[j] << 16)
                        + w2 * __builtin_bit_cast(float, p2[j] << 16)
                        + w3 * __builtin_bit_cast(float, p3[j] << 16);
            acc[2*j+1] += w0 * __builtin_bit_cast(float, p0[j] & 0xffff0000u)
                        + w1 * __builtin_bit_cast(float, p1[j] & 0xffff0000u)
                        + w2 * __builtin_bit_cast(float, p2[j] & 0xffff0000u)
                        + w3 * __builtin_bit_cast(float, p3[j] & 0xffff0000u);
        }
    }
    for (; i < e; i += 2) {
        int   c0 = col[i];
        float w0 = ew[i];
        uint4 v0 = *(const uint4*)(h0 + (size_t)c0 * NHID + fl * 8);
        const unsigned* p0 = &v0.x;
        #pragma unroll
        for (int j = 0; j < 4; j++) {
            acc[2*j+0] += w0 * __builtin_bit_cast(float, p0[j] << 16);
            acc[2*j+1] += w0 * __builtin_bit_cast(float, p0[j] & 0xffff0000u);
        }
    }

    #pragma unroll
    for (int j = 0; j < 8; j++)
        acc[j] += __shfl_down(acc[j], 32, 64);

    if (half == 0) {
        unsigned short u[8];
        #pragma unroll
        for (int j = 0; j < 8; j++) {
            float v = acc[j] + b1[fl * 8 + j];
            u[j] = f2bf(v > 0.f ? v : 0.f);
        }
        uint4 o;
        o.x = (unsigned)u[0] | ((unsigned)u[1] << 16);
        o.y = (unsigned)u[2] | ((unsigned)u[3] << 16);
        o.z = (unsigned)u[4] | ((unsigned)u[5] << 16);
        o.w = (unsigned)u[6] | ((unsigned)u[7] << 16);
        *(uint4*)(h1 + (size_t)n * NHID + fl * 8) = o;
    }
}

// ---------------------------------------------------------------------------
// SpMM2 + bias: one wave per node, h2 is bf16 [MP][64]. Quarter-wave (16
// lanes x uint2 = 4 bf16) per edge -> 4 edges per load instr, unroll x2.
// ---------------------------------------------------------------------------
__global__ __launch_bounds__(256) void spmm2_wave(const __bf16* __restrict__ h2,
                                                  const float* __restrict__ ew,
                                                  const int* __restrict__ col,
                                                  const int* __restrict__ rp,
                                                  const float* __restrict__ b2,
                                                  float* __restrict__ out) {
    const int n    = blockIdx.x * 4 + (threadIdx.x >> 6);
    const int lane = threadIdx.x & 63;
    const int g    = lane >> 4;       // edge group 0..3
    const int fl   = lane & 15;       // 4 feats per lane
    const int s = rp[n], e = rp[n + 1];

    float a0 = 0.f, a1 = 0.f, a2 = 0.f, a3 = 0.f;
    int i = s + g;
    for (; i + 4 < e; i += 8) {
        int   c0 = col[i];     float w0 = ew[i];
        int   c1 = col[i + 4]; float w1 = ew[i + 4];
        uint2 v0 = *(const uint2*)(h2 + (size_t)c0 * NOUT + fl * 4);
        uint2 v1 = *(const uint2*)(h2 + (size_t)c1 * NOUT + fl * 4);
        a0 += w0 * __builtin_bit_cast(float, v0.x << 16)
            + w1 * __builtin_bit_cast(float, v1.x << 16);
        a1 += w0 * __builtin_bit_cast(float, v0.x & 0xffff0000u)
            + w1 * __builtin_bit_cast(float, v1.x & 0xffff0000u);
        a2 += w0 * __builtin_bit_cast(float, v0.y << 16)
            + w1 * __builtin_bit_cast(float, v1.y << 16);
        a3 += w0 * __builtin_bit_cast(float, v0.y & 0xffff0000u)
            + w1 * __builtin_bit_cast(float, v1.y & 0xffff0000u);
    }
    for (; i < e; i += 4) {
        int   c0 = col[i]; float w0 = ew[i];
        uint2 v0 = *(const uint2*)(h2 + (size_t)c0 * NOUT + fl * 4);
        a0 += w0 * __builtin_bit_cast(float, v0.x << 16);
        a1 += w0 * __builtin_bit_cast(float, v0.x & 0xffff0000u);
        a2 += w0 * __builtin_bit_cast(float, v0.y << 16);
        a3 += w0 * __builtin_bit_cast(float, v0.y & 0xffff0000u);
    }

    a0 += __shfl_down(a0, 32, 64); a1 += __shfl_down(a1, 32, 64);
    a2 += __shfl_down(a2, 32, 64); a3 += __shfl_down(a3, 32, 64);
    a0 += __shfl_down(a0, 16, 64); a1 += __shfl_down(a1, 16, 64);
    a2 += __shfl_down(a2, 16, 64); a3 += __shfl_down(a3, 16, 64);

    if (lane < 16) {
        float4 bb = *(const float4*)(b2 + fl * 4);
        float4 o = make_float4(a0 + bb.x, a1 + bb.y, a2 + bb.z, a3 + bb.w);
        *(float4*)(out + (size_t)n * NOUT + fl * 4) = o;
    }
}

// ---------------------------------------------------------------------------
extern "C" void kernel_launch(void* const* d_in, const int* in_sizes, int n_in,
                              void* d_out, int out_size, void* d_ws, size_t ws_size,
                              hipStream_t stream) {
    const float* x   = (const float*)d_in[0];
    const float* w1  = (const float*)d_in[1];
    const float* b1  = (const float*)d_in[2];
    const float* w2  = (const float*)d_in[3];
    const float* b2  = (const float*)d_in[4];
    const float* ew  = (const float*)d_in[5];
    const int*   row = (const int*)d_in[6];
    const int*   col = (const int*)d_in[7];
    float* out = (float*)d_out;

    char* ws = (char*)d_ws;
    size_t off = 0;
    int*    rp  = (int*)(ws + off);   off += 256 * 1024;
    __bf16* w1t = (__bf16*)(ws + off); off += (size_t)NHID * NFEAT * 2;   // 256 KB
    __bf16* w2t = (__bf16*)(ws + off); off += (size_t)NOUT * NHID * 2;    // 32 KB
    __bf16* h0  = (__bf16*)(ws + off); off += (size_t)MP * NHID * 2;      // 25.6 MB
    __bf16* h1  = (__bf16*)(ws + off); off += (size_t)MP * NHID * 2;      // 25.6 MB
    __bf16* h2  = (__bf16*)(ws + off);                                     // 6.4 MB

    prep<<<820, 256, 0, stream>>>(row, rp, w1, w1t, w2, w2t, h1);

    // layer 1 dense (fused fp32->bf16 on A): h0 = bf16(x) @ w1
    gemm1_direct<<<MP / 64, 256, 0, stream>>>(x, w1t, h0);

    // layer 1 sparse: h1 = relu(adj @ h0 + b1)
    spmm1_wave<<<N_NODES / 4, 256, 0, stream>>>(h0, ew, col, rp, b1, h1);

    // layer 2 dense: h2 = h1 @ w2
    gemm2_direct<<<MP / 64, 256, 0, stream>>>(h1, w2t, h2);

    // layer 2 sparse: out = adj @ h2 + b2
    spmm2_wave<<<N_NODES / 4, 256, 0, stream>>>(h2, ew, col, rp, b2, out);
}

// Round 7
// 280.662 us; speedup vs baseline: 1.5640x; 1.5640x over previous
//
#include <hip/hip_runtime.h>

#define N_NODES 50000
#define MP      50048        // N_NODES padded to multiple of 128
#define N_EDGES 800000
#define NFEAT   512
#define NHID    256
#define NOUT    64

typedef __bf16 bf16x8 __attribute__((ext_vector_type(8)));
typedef float  f32x4  __attribute__((ext_vector_type(4)));

// async global->LDS, 16B per lane. LDS dest = wave-uniform base + lane*16.
#define GLOAD_LDS16(g, l) __builtin_amdgcn_global_load_lds(                    \
    (const __attribute__((address_space(1))) void*)(g),                        \
    (__attribute__((address_space(3))) void*)(l), 16, 0, 0)

__device__ __forceinline__ unsigned short f2bf(float f) {
    __bf16 b = (__bf16)f;                       // RNE
    return __builtin_bit_cast(unsigned short, b);
}

__device__ __forceinline__ uint4 pack8u(float4 a, float4 b) {
    uint4 o;
    o.x = (unsigned)f2bf(a.x) | ((unsigned)f2bf(a.y) << 16);
    o.y = (unsigned)f2bf(a.z) | ((unsigned)f2bf(a.w) << 16);
    o.z = (unsigned)f2bf(b.x) | ((unsigned)f2bf(b.y) << 16);
    o.w = (unsigned)f2bf(b.z) | ((unsigned)f2bf(b.w) << 16);
    return o;
}

// ---------------------------------------------------------------------------
// prep: fused rowptr + w1 transpose + w2 transpose + h1 pad zero. 820 blocks.
// ---------------------------------------------------------------------------
__global__ __launch_bounds__(256) void prep(const int* __restrict__ row,
                                            int* __restrict__ rp,
                                            const float* __restrict__ w1,
                                            __bf16* __restrict__ w1t,
                                            const float* __restrict__ w2,
                                            __bf16* __restrict__ w2t,
                                            __bf16* __restrict__ h1) {
    const int b = blockIdx.x, t = threadIdx.x;
    if (b < 196) {
        int r = b * 256 + t;
        if (r <= N_NODES) {
            int lo = 0, hi = N_EDGES;
            while (lo < hi) {
                int mid = (lo + hi) >> 1;
                if (row[mid] < r) lo = mid + 1; else hi = mid;
            }
            rp[r] = lo;
        }
    } else if (b < 708) {
        int o = (b - 196) * 256 + t;          // n = o>>9, k = o&511
        w1t[o] = (__bf16)w1[(size_t)(o & 511) * NHID + (o >> 9)];
    } else if (b < 772) {
        int o = (b - 708) * 256 + t;          // n = o>>8, k = o&255
        w2t[o] = (__bf16)w2[(size_t)(o & 255) * NOUT + (o >> 8)];
    } else {
        int o = (b - 772) * 256 + t;
        h1[(size_t)N_NODES * NHID + o] = (__bf16)0.f;
    }
}

// ---------------------------------------------------------------------------
// GEMM1, software-pipelined: C[MP][256] bf16 = bf16(X fp32) @ w1t[256][512]^T
// 64x256 tile, BK=32, grid 782. Double-buffered LDS, ONE barrier/iter:
// B[k+1] global_load_lds + A[k+1] reg-loads are issued right AFTER the
// barrier and land during compute_k, so the next barrier's vmcnt(0) drain
// finds them (mostly) complete.
// ---------------------------------------------------------------------------
__global__ __launch_bounds__(256) void gemm1_pipe(const float* __restrict__ X,
                                                  const __bf16* __restrict__ Bt,
                                                  __bf16* __restrict__ C) {
    __shared__ __bf16 As[2][64 * 32];     // 2 x 4 KB
    __shared__ __bf16 Bs[2][256 * 32];    // 2 x 16 KB
    const int t = threadIdx.x;
    const int w = t >> 6, l = t & 63;
    const int wm = w >> 1, wn = w & 1;
    const int ml = l & 15, quad = l >> 4;
    const int row0 = blockIdx.x * 64;

    // A chunk owned by this thread: row ar, 8-col group ac
    const int ar = t >> 2;
    const int ac = (t & 3) * 8;
    const bool aval = (row0 + ar < N_NODES);
    const float* asrc = X + (size_t)(row0 + ar) * NFEAT + ac;

    f32x4 acc[2][8] = {};
    const float4 z4 = make_float4(0.f, 0.f, 0.f, 0.f);

    // prologue: B[0] -> Bs[0]; A[0] -> regs
    #pragma unroll
    for (int it = 0; it < 4; it++) {
        int q = it * 256 + w * 64 + l;        // chunk 0..1023 over [256][32]
        int r = q >> 2, cc = (q & 3) * 8;
        GLOAD_LDS16(Bt + (size_t)r * NFEAT + cc,
                    &Bs[0][(size_t)(it * 256 + w * 64) * 8]);
    }
    float4 pa = z4, pb = z4;
    if (aval) { pa = *(const float4*)asrc; pb = *(const float4*)(asrc + 4); }

    int buf = 0;
    for (int k0 = 0; k0 < NFEAT; k0 += 32) {
        // stage A: convert regs, one ds_write_b128 per thread
        *(uint4*)(&As[buf][(size_t)t * 8]) = pack8u(pa, pb);
        __syncthreads();   // drains B[buf] (issued one compute-phase ago) + As writes

        if (k0 + 32 < NFEAT) {
            // issue next B tile into the other buffer
            #pragma unroll
            for (int it = 0; it < 4; it++) {
                int q = it * 256 + w * 64 + l;
                int r = q >> 2, cc = (q & 3) * 8;
                GLOAD_LDS16(Bt + (size_t)r * NFEAT + (k0 + 32) + cc,
                            &Bs[buf ^ 1][(size_t)(it * 256 + w * 64) * 8]);
            }
            // next A into regs
            if (aval) {
                pa = *(const float4*)(asrc + k0 + 32);
                pb = *(const float4*)(asrc + k0 + 36);
            }
        }

        bf16x8 af[2], bfr[8];
        #pragma unroll
        for (int mi = 0; mi < 2; mi++)
            af[mi] = *(const bf16x8*)(&As[buf][(wm * 32 + mi * 16 + ml) * 32 + quad * 8]);
        #pragma unroll
        for (int ni = 0; ni < 8; ni++)
            bfr[ni] = *(const bf16x8*)(&Bs[buf][(wn * 128 + ni * 16 + ml) * 32 + quad * 8]);
        #pragma unroll
        for (int mi = 0; mi < 2; mi++)
            #pragma unroll
            for (int ni = 0; ni < 8; ni++)
                acc[mi][ni] = __builtin_amdgcn_mfma_f32_16x16x32_bf16(
                    af[mi], bfr[ni], acc[mi][ni], 0, 0, 0);
        buf ^= 1;
    }

    // C/D layout: col = lane&15, row = quad*4 + reg
    #pragma unroll
    for (int mi = 0; mi < 2; mi++) {
        int gr = row0 + wm * 32 + mi * 16 + quad * 4;
        #pragma unroll
        for (int ni = 0; ni < 8; ni++) {
            int gc = wn * 128 + ni * 16 + ml;
            #pragma unroll
            for (int r2 = 0; r2 < 4; r2++)
                C[(size_t)(gr + r2) * NHID + gc] = (__bf16)acc[mi][ni][r2];
        }
    }
}

// ---------------------------------------------------------------------------
// GEMM2, software-pipelined: C[MP][64] bf16 = h1[MP][256] @ w2t[64][256]^T.
// 64x64 tile, grid 782. w2t persists in LDS whole-kernel, stored K-tile-major
// [kt][64][32] so compute reads have 64 B ml-stride (2-way = free).
// A double-buffered via global_load_lds, ONE barrier per iter.
// ---------------------------------------------------------------------------
__global__ __launch_bounds__(256) void gemm2_pipe(const __bf16* __restrict__ A,
                                                  const __bf16* __restrict__ Bt,
                                                  __bf16* __restrict__ C) {
    __shared__ __bf16 As[2][64 * 32];     // 2 x 4 KB
    __shared__ __bf16 Bsf[8][64 * 32];    // full w2t, K-tile-major, 32 KB
    const int t = threadIdx.x;
    const int w = t >> 6, l = t & 63;
    const int ml = l & 15, quad = l >> 4;
    const int row0 = blockIdx.x * 64;

    // prologue: full B (32 wave-instrs, 8 per wave) + A[0]
    #pragma unroll
    for (int it = 0; it < 8; it++) {
        int wi = it * 4 + w;                 // 0..31
        int kt = wi >> 2, r0 = (wi & 3) * 16;
        int r = r0 + (l >> 2), cc = (l & 3) * 8;
        GLOAD_LDS16(Bt + (size_t)r * NHID + kt * 32 + cc,
                    &Bsf[kt][(size_t)r0 * 32] + (size_t)0);  // wave base; +l*16B implicit
    }
    {
        int q = w * 64 + l;                  // A chunk over [64][32]
        int r = q >> 2, cc = (q & 3) * 8;
        GLOAD_LDS16(A + (size_t)(row0 + r) * NHID + cc,
                    &As[0][(size_t)(w * 64) * 8]);
    }

    f32x4 acc[4] = {};
    int buf = 0;
    for (int k0 = 0; k0 < NHID; k0 += 32) {
        __syncthreads();   // drains A[buf] (+ B on first iter)
        if (k0 + 32 < NHID) {
            int q = w * 64 + l;
            int r = q >> 2, cc = (q & 3) * 8;
            GLOAD_LDS16(A + (size_t)(row0 + r) * NHID + (k0 + 32) + cc,
                        &As[buf ^ 1][(size_t)(w * 64) * 8]);
        }
        const int kt = k0 >> 5;
        bf16x8 af = *(const bf16x8*)(&As[buf][(w * 16 + ml) * 32 + quad * 8]);
        bf16x8 bfr[4];
        #pragma unroll
        for (int ni = 0; ni < 4; ni++)
            bfr[ni] = *(const bf16x8*)(&Bsf[kt][(ni * 16 + ml) * 32 + quad * 8]);
        #pragma unroll
        for (int ni = 0; ni < 4; ni++)
            acc[ni] = __builtin_amdgcn_mfma_f32_16x16x32_bf16(
                af, bfr[ni], acc[ni], 0, 0, 0);
        buf ^= 1;
    }

    #pragma unroll
    for (int ni = 0; ni < 4; ni++) {
        int gc = ni * 16 + ml;
        #pragma unroll
        for (int r2 = 0; r2 < 4; r2++) {
            int gr = row0 + w * 16 + quad * 4 + r2;
            C[(size_t)gr * NOUT + gc] = (__bf16)acc[ni][r2];
        }
    }
}

// ---------------------------------------------------------------------------
// SpMM1 + bias + ReLU: one wave per node. Half-wave (32 lanes) per edge,
// 16 B/lane (8 bf16 feats). Unrolled x4 -> 8 edges in flight per wave.
// ---------------------------------------------------------------------------
__global__ __launch_bounds__(256) void spmm1_wave(const __bf16* __restrict__ h0,
                                                  const float* __restrict__ ew,
                                                  const int* __restrict__ col,
                                                  const int* __restrict__ rp,
                                                  const float* __restrict__ b1,
                                                  __bf16* __restrict__ h1) {
    const int n    = blockIdx.x * 4 + (threadIdx.x >> 6);
    const int lane = threadIdx.x & 63;
    const int half = lane >> 5;
    const int fl   = lane & 31;       // 8 bf16 feats per lane
    const int s = rp[n], e = rp[n + 1];

    float acc[8] = {};
    int i = s + half;
    for (; i + 6 < e; i += 8) {
        int   c0 = col[i],     c1 = col[i + 2], c2 = col[i + 4], c3 = col[i + 6];
        float w0 = ew[i],      w1 = ew[i + 2],  w2 = ew[i + 4],  w3 = ew[i + 6];
        uint4 v0 = *(const uint4*)(h0 + (size_t)c0 * NHID + fl * 8);
        uint4 v1 = *(const uint4*)(h0 + (size_t)c1 * NHID + fl * 8);
        uint4 v2 = *(const uint4*)(h0 + (size_t)c2 * NHID + fl * 8);
        uint4 v3 = *(const uint4*)(h0 + (size_t)c3 * NHID + fl * 8);
        const unsigned* p0 = &v0.x; const unsigned* p1 = &v1.x;
        const unsigned* p2 = &v2.x; const unsigned* p3 = &v3.x;
        #pragma unroll
        for (int j = 0; j < 4; j++) {
            acc[2*j+0] += w0 * __builtin_bit_cast(float, p0[j] << 16)
                        + w1 * __builtin_bit_cast(float, p1[j] << 16)
                        + w2 * __builtin_bit_cast(float, p2[j] << 16)
                        + w3 * __builtin_bit_cast(float, p3[j] << 16);
            acc[2*j+1] += w0 * __builtin_bit_cast(float, p0[j] & 0xffff0000u)
                        + w1 * __builtin_bit_cast(float, p1[j] & 0xffff0000u)
                        + w2 * __builtin_bit_cast(float, p2[j] & 0xffff0000u)
                        + w3 * __builtin_bit_cast(float, p3[j] & 0xffff0000u);
        }
    }
    for (; i < e; i += 2) {
        int   c0 = col[i];
        float w0 = ew[i];
        uint4 v0 = *(const uint4*)(h0 + (size_t)c0 * NHID + fl * 8);
        const unsigned* p0 = &v0.x;
        #pragma unroll
        for (int j = 0; j < 4; j++) {
            acc[2*j+0] += w0 * __builtin_bit_cast(float, p0[j] << 16);
            acc[2*j+1] += w0 * __builtin_bit_cast(float, p0[j] & 0xffff0000u);
        }
    }

    #pragma unroll
    for (int j = 0; j < 8; j++)
        acc[j] += __shfl_down(acc[j], 32, 64);

    if (half == 0) {
        unsigned short u[8];
        #pragma unroll
        for (int j = 0; j < 8; j++) {
            float v = acc[j] + b1[fl * 8 + j];
            u[j] = f2bf(v > 0.f ? v : 0.f);
        }
        uint4 o;
        o.x = (unsigned)u[0] | ((unsigned)u[1] << 16);
        o.y = (unsigned)u[2] | ((unsigned)u[3] << 16);
        o.z = (unsigned)u[4] | ((unsigned)u[5] << 16);
        o.w = (unsigned)u[6] | ((unsigned)u[7] << 16);
        *(uint4*)(h1 + (size_t)n * NHID + fl * 8) = o;
    }
}

// ---------------------------------------------------------------------------
// SpMM2 + bias: one wave per node, h2 is bf16 [MP][64]. Quarter-wave (16
// lanes x uint2 = 4 bf16) per edge -> 4 edges per load instr, unroll x2.
// ---------------------------------------------------------------------------
__global__ __launch_bounds__(256) void spmm2_wave(const __bf16* __restrict__ h2,
                                                  const float* __restrict__ ew,
                                                  const int* __restrict__ col,
                                                  const int* __restrict__ rp,
                                                  const float* __restrict__ b2,
                                                  float* __restrict__ out) {
    const int n    = blockIdx.x * 4 + (threadIdx.x >> 6);
    const int lane = threadIdx.x & 63;
    const int g    = lane >> 4;       // edge group 0..3
    const int fl   = lane & 15;       // 4 feats per lane
    const int s = rp[n], e = rp[n + 1];

    float a0 = 0.f, a1 = 0.f, a2 = 0.f, a3 = 0.f;
    int i = s + g;
    for (; i + 4 < e; i += 8) {
        int   c0 = col[i];     float w0 = ew[i];
        int   c1 = col[i + 4]; float w1 = ew[i + 4];
        uint2 v0 = *(const uint2*)(h2 + (size_t)c0 * NOUT + fl * 4);
        uint2 v1 = *(const uint2*)(h2 + (size_t)c1 * NOUT + fl * 4);
        a0 += w0 * __builtin_bit_cast(float, v0.x << 16)
            + w1 * __builtin_bit_cast(float, v1.x << 16);
        a1 += w0 * __builtin_bit_cast(float, v0.x & 0xffff0000u)
            + w1 * __builtin_bit_cast(float, v1.x & 0xffff0000u);
        a2 += w0 * __builtin_bit_cast(float, v0.y << 16)
            + w1 * __builtin_bit_cast(float, v1.y << 16);
        a3 += w0 * __builtin_bit_cast(float, v0.y & 0xffff0000u)
            + w1 * __builtin_bit_cast(float, v1.y & 0xffff0000u);
    }
    for (; i < e; i += 4) {
        int   c0 = col[i]; float w0 = ew[i];
        uint2 v0 = *(const uint2*)(h2 + (size_t)c0 * NOUT + fl * 4);
        a0 += w0 * __builtin_bit_cast(float, v0.x << 16);
        a1 += w0 * __builtin_bit_cast(float, v0.x & 0xffff0000u);
        a2 += w0 * __builtin_bit_cast(float, v0.y << 16);
        a3 += w0 * __builtin_bit_cast(float, v0.y & 0xffff0000u);
    }

    a0 += __shfl_down(a0, 32, 64); a1 += __shfl_down(a1, 32, 64);
    a2 += __shfl_down(a2, 32, 64); a3 += __shfl_down(a3, 32, 64);
    a0 += __shfl_down(a0, 16, 64); a1 += __shfl_down(a1, 16, 64);
    a2 += __shfl_down(a2, 16, 64); a3 += __shfl_down(a3, 16, 64);

    if (lane < 16) {
        float4 bb = *(const float4*)(b2 + fl * 4);
        float4 o = make_float4(a0 + bb.x, a1 + bb.y, a2 + bb.z, a3 + bb.w);
        *(float4*)(out + (size_t)n * NOUT + fl * 4) = o;
    }
}

// ---------------------------------------------------------------------------
extern "C" void kernel_launch(void* const* d_in, const int* in_sizes, int n_in,
                              void* d_out, int out_size, void* d_ws, size_t ws_size,
                              hipStream_t stream) {
    const float* x   = (const float*)d_in[0];
    const float* w1  = (const float*)d_in[1];
    const float* b1  = (const float*)d_in[2];
    const float* w2  = (const float*)d_in[3];
    const float* b2  = (const float*)d_in[4];
    const float* ew  = (const float*)d_in[5];
    const int*   row = (const int*)d_in[6];
    const int*   col = (const int*)d_in[7];
    float* out = (float*)d_out;

    char* ws = (char*)d_ws;
    size_t off = 0;
    int*    rp  = (int*)(ws + off);   off += 256 * 1024;
    __bf16* w1t = (__bf16*)(ws + off); off += (size_t)NHID * NFEAT * 2;   // 256 KB
    __bf16* w2t = (__bf16*)(ws + off); off += (size_t)NOUT * NHID * 2;    // 32 KB
    __bf16* h0  = (__bf16*)(ws + off); off += (size_t)MP * NHID * 2;      // 25.6 MB
    __bf16* h1  = (__bf16*)(ws + off); off += (size_t)MP * NHID * 2;      // 25.6 MB
    __bf16* h2  = (__bf16*)(ws + off);                                     // 6.4 MB

    prep<<<820, 256, 0, stream>>>(row, rp, w1, w1t, w2, w2t, h1);

    // layer 1 dense (fused fp32->bf16 on A): h0 = bf16(x) @ w1
    gemm1_pipe<<<MP / 64, 256, 0, stream>>>(x, w1t, h0);

    // layer 1 sparse: h1 = relu(adj @ h0 + b1)
    spmm1_wave<<<N_NODES / 4, 256, 0, stream>>>(h0, ew, col, rp, b1, h1);

    // layer 2 dense: h2 = h1 @ w2
    gemm2_pipe<<<MP / 64, 256, 0, stream>>>(h1, w2t, h2);

    // layer 2 sparse: out = adj @ h2 + b2
    spmm2_wave<<<N_NODES / 4, 256, 0, stream>>>(h2, ew, col, rp, b2, out);
}